// Round 12
// baseline (1239.536 us; speedup 1.0000x reference)
//
#include <hip/hip_runtime.h>
#include <hip/hip_bf16.h>
#include <math.h>

#define TT 2048
#define HID 2560
#define NH 40
#define NOPE 64
#define ROPE 32
#define VDIM 64
#define QLORA 768
#define KVLORA 256
#define DQK 288            // KVLORA + ROPE
#define QHD 96             // NOPE + ROPE
#define EPS 1e-5f
#define THETA 10000.0f

typedef __attribute__((ext_vector_type(8))) short bf16x8;
typedef __attribute__((ext_vector_type(4))) float f32x4;
typedef __attribute__((address_space(1))) const void* gas_t;
typedef __attribute__((address_space(3))) void* las_t;

static __device__ __forceinline__ ushort f2bf(float x) {
    __hip_bfloat16 b = __float2bfloat16(x);
    return *reinterpret_cast<ushort*>(&b);
}

// ---------------- flat fp32 -> bf16 cast ----------------
__global__ __launch_bounds__(256) void cast_bf16(const float* __restrict__ x,
                                                 ushort* __restrict__ y, int n) {
    int i = (blockIdx.x * 256 + threadIdx.x) * 4;
    if (i + 3 < n) {
        float4 v = *(const float4*)(x + i);
        y[i]     = f2bf(v.x);
        y[i + 1] = f2bf(v.y);
        y[i + 2] = f2bf(v.z);
        y[i + 3] = f2bf(v.w);
    }
}

// ------------- transpose + cast: w (K x N fp32) -> wt (N x K bf16) -------------
__global__ __launch_bounds__(256) void transpose_cast(const float* __restrict__ w,
                                                      ushort* __restrict__ wt,
                                                      int K, int N) {
    __shared__ float tile[32][33];
    int bn = blockIdx.x * 32, bk = blockIdx.y * 32;
    int tx = threadIdx.x % 32, ty = threadIdx.x / 32;   // 32 x 8
    #pragma unroll
    for (int i = 0; i < 32; i += 8) {
        int k = bk + ty + i, n = bn + tx;
        if (k < K && n < N) tile[ty + i][tx] = w[(size_t)k * N + n];
    }
    __syncthreads();
    #pragma unroll
    for (int i = 0; i < 32; i += 8) {
        int n = bn + ty + i, k = bk + tx;
        if (n < N && k < K) wt[(size_t)n * K + k] = f2bf(tile[tx][ty + i]);
    }
}

// ---- per-head transpose: w_vc (H, K=256, V=64) fp32 -> w_vct (H, V=64, K=256) bf16 ----
__global__ __launch_bounds__(256) void transpose_vc(const float* __restrict__ w,
                                                    ushort* __restrict__ wt) {
    __shared__ float tile[32][33];
    int h = blockIdx.z;
    const float* src = w + (size_t)h * KVLORA * VDIM;
    ushort* dst = wt + (size_t)h * VDIM * KVLORA;
    int bn = blockIdx.x * 32, bk = blockIdx.y * 32;     // n over V, k over KVLORA
    int tx = threadIdx.x % 32, ty = threadIdx.x / 32;
    #pragma unroll
    for (int i = 0; i < 32; i += 8)
        tile[ty + i][tx] = src[(size_t)(bk + ty + i) * VDIM + bn + tx];
    __syncthreads();
    #pragma unroll
    for (int i = 0; i < 32; i += 8)
        dst[(size_t)(bn + ty + i) * KVLORA + bk + tx] = f2bf(tile[tx][ty + i]);
}

// ------- bf16 MFMA GEMM (m97 structure): C(MxN,f32) = A(MxK,bf16) @ Bt(NxK,bf16)^T -------
__global__ __launch_bounds__(256, 2) void gemm_bf16(const ushort* __restrict__ A,
                                                    const ushort* __restrict__ Bt,
                                                    float* __restrict__ C,
                                                    int M, int N, int K) {
    __shared__ ushort As[128 * 32];
    __shared__ ushort Bs[128 * 32];
    const int tid  = threadIdx.x;
    const int lane = tid & 63;
    const int wv   = tid >> 6;
    const int col  = lane & 15;
    const int quad = lane >> 4;
    const int m0 = blockIdx.y * 128, n0 = blockIdx.x * 128;
    const int wr = (wv >> 1) * 64, wc = (wv & 1) * 64;

    f32x4 acc[4][4];
    #pragma unroll
    for (int i = 0; i < 4; i++)
        #pragma unroll
        for (int j = 0; j < 4; j++) acc[i][j] = (f32x4){0.f, 0.f, 0.f, 0.f};

    for (int k0 = 0; k0 < K; k0 += 32) {
        #pragma unroll
        for (int j = 0; j < 2; j++) {
            int slot = wv * 128 + j * 64 + lane;     // 0..511
            int row  = slot >> 2;
            int ch   = slot & 3;
            const ushort* ga = A + (size_t)(m0 + row) * K + k0 + ch * 8;
            __builtin_amdgcn_global_load_lds((gas_t)ga, (las_t)(As + slot * 8), 16, 0, 0);
            int brow = n0 + row; if (brow >= N) brow = N - 1;   // clamp (edge tiles)
            const ushort* gb = Bt + (size_t)brow * K + k0 + ch * 8;
            __builtin_amdgcn_global_load_lds((gas_t)gb, (las_t)(Bs + slot * 8), 16, 0, 0);
        }
        __syncthreads();
        bf16x8 af[4], bfr[4];
        #pragma unroll
        for (int i = 0; i < 4; i++)
            af[i] = *(const bf16x8*)(As + (wr + i * 16 + col) * 32 + quad * 8);
        #pragma unroll
        for (int j = 0; j < 4; j++)
            bfr[j] = *(const bf16x8*)(Bs + (wc + j * 16 + col) * 32 + quad * 8);
        #pragma unroll
        for (int i = 0; i < 4; i++)
            #pragma unroll
            for (int j = 0; j < 4; j++)
                acc[i][j] = __builtin_amdgcn_mfma_f32_16x16x32_bf16(af[i], bfr[j], acc[i][j], 0, 0, 0);
        __syncthreads();
    }
    #pragma unroll
    for (int i = 0; i < 4; i++) {
        int gr = m0 + wr + i * 16 + quad * 4;
        #pragma unroll
        for (int j = 0; j < 4; j++) {
            int gc = n0 + wc + j * 16 + col;
            if (gc < N) {
                #pragma unroll
                for (int r = 0; r < 4; r++)
                    C[(size_t)(gr + r) * N + gc] = acc[i][j][r];
            }
        }
    }
}

// ------- 128x64-tile variant for narrow-N GEMMs (N=768, N=288): better grid occupancy -------
__global__ __launch_bounds__(256, 4) void gemm_bf16_n64(const ushort* __restrict__ A,
                                                        const ushort* __restrict__ Bt,
                                                        float* __restrict__ C,
                                                        int M, int N, int K) {
    __shared__ ushort As[128 * 32];
    __shared__ ushort Bs[64 * 32];
    const int tid  = threadIdx.x;
    const int lane = tid & 63;
    const int wv   = tid >> 6;
    const int col  = lane & 15;
    const int quad = lane >> 4;
    const int m0 = blockIdx.y * 128, n0 = blockIdx.x * 64;
    const int wr = wv * 32;

    f32x4 acc[2][4];
    #pragma unroll
    for (int i = 0; i < 2; i++)
        #pragma unroll
        for (int j = 0; j < 4; j++) acc[i][j] = (f32x4){0.f, 0.f, 0.f, 0.f};

    for (int k0 = 0; k0 < K; k0 += 32) {
        #pragma unroll
        for (int j = 0; j < 2; j++) {                // A: 512 slots, 2/thread
            int slot = j * 256 + tid;
            int row  = slot >> 2;
            int ch   = slot & 3;
            const ushort* ga = A + (size_t)(m0 + row) * K + k0 + ch * 8;
            __builtin_amdgcn_global_load_lds((gas_t)ga, (las_t)(As + slot * 8), 16, 0, 0);
        }
        {                                            // B: 256 slots, 1/thread
            int row = tid >> 2;
            int ch  = tid & 3;
            int brow = n0 + row; if (brow >= N) brow = N - 1;
            const ushort* gb = Bt + (size_t)brow * K + k0 + ch * 8;
            __builtin_amdgcn_global_load_lds((gas_t)gb, (las_t)(Bs + tid * 8), 16, 0, 0);
        }
        __syncthreads();
        bf16x8 af[2], bfr[4];
        #pragma unroll
        for (int i = 0; i < 2; i++)
            af[i] = *(const bf16x8*)(As + (wr + i * 16 + col) * 32 + quad * 8);
        #pragma unroll
        for (int j = 0; j < 4; j++)
            bfr[j] = *(const bf16x8*)(Bs + (j * 16 + col) * 32 + quad * 8);
        #pragma unroll
        for (int i = 0; i < 2; i++)
            #pragma unroll
            for (int j = 0; j < 4; j++)
                acc[i][j] = __builtin_amdgcn_mfma_f32_16x16x32_bf16(af[i], bfr[j], acc[i][j], 0, 0, 0);
        __syncthreads();
    }
    #pragma unroll
    for (int i = 0; i < 2; i++) {
        int gr = m0 + wr + i * 16 + quad * 4;
        #pragma unroll
        for (int j = 0; j < 4; j++) {
            int gc = n0 + j * 16 + col;
            if (gc < N) {
                #pragma unroll
                for (int r = 0; r < 4; r++)
                    C[(size_t)(gr + r) * N + gc] = acc[i][j][r];
            }
        }
    }
}

// ---------------- RMS norm: fp32 in, bf16 out ----------------
__global__ __launch_bounds__(256) void rms_qa(const float* __restrict__ x,
                                              const float* __restrict__ g,
                                              ushort* __restrict__ y) {
    int t = blockIdx.x, tid = threadIdx.x;
    __shared__ float red[256];
    __shared__ float s_inv;
    const float* row = x + (size_t)t * QLORA;
    float ss = 0.f;
    for (int i = tid; i < QLORA; i += 256) { float v = row[i]; ss += v * v; }
    red[tid] = ss; __syncthreads();
    for (int s = 128; s > 0; s >>= 1) { if (tid < s) red[tid] += red[tid + s]; __syncthreads(); }
    if (tid == 0) s_inv = rsqrtf(red[0] / (float)QLORA + EPS);
    __syncthreads();
    float si = s_inv;
    ushort* orow = y + (size_t)t * QLORA;
    for (int i = tid; i < QLORA; i += 256) orow[i] = f2bf(row[i] * si * g[i]);
}

// ------- latent post: RMS first 256, RoPE last 32 -> bf16 kin_bf (T x 288) -------
__global__ __launch_bounds__(256) void kin_post(const float* __restrict__ kin,
                                                const float* __restrict__ g,
                                                const int* __restrict__ positions,
                                                ushort* __restrict__ kin_bf) {
    int t = blockIdx.x, tid = threadIdx.x;
    __shared__ float red[256];
    __shared__ float s_inv;
    const float* row = kin + (size_t)t * DQK;
    float v = row[tid];
    red[tid] = v * v; __syncthreads();
    for (int s = 128; s > 0; s >>= 1) { if (tid < s) red[tid] += red[tid + s]; __syncthreads(); }
    if (tid == 0) s_inv = rsqrtf(red[0] / (float)KVLORA + EPS);
    __syncthreads();
    ushort* orow = kin_bf + (size_t)t * DQK;
    orow[tid] = f2bf(v * s_inv * g[tid]);
    if (tid < 16) {
        float pos = (float)positions[t];
        float freq = powf(THETA, -(float)tid / 16.0f);
        float f = pos * freq;
        float c = cosf(f), s = sinf(f);
        float x1 = row[KVLORA + tid], x2 = row[KVLORA + 16 + tid];
        orow[KVLORA + tid]      = f2bf(x1 * c - x2 * s);
        orow[KVLORA + 16 + tid] = f2bf(x2 * c + x1 * s);
    }
}

// --- q_in build (tiled: 16 t-rows per block, w_kc[h] read once per block) ---
#define QTB 16
__global__ __launch_bounds__(256) void build_qin(const float* __restrict__ q,
                                                 const float* __restrict__ w_kc,
                                                 const int* __restrict__ positions,
                                                 ushort* __restrict__ qin) {
    int tb = blockIdx.x * QTB, h = blockIdx.y, tid = threadIdx.x;
    const float scale = 0.10206207261596577f;   // 1/sqrt(96), folded into Q
    __shared__ float qn[QTB][NOPE];
    __shared__ float qp[QTB][ROPE];
    // load 16 q rows (96 floats each)
    for (int i = tid; i < QTB * QHD; i += 256) {
        int r = i / QHD, cidx = i % QHD;
        float v = q[(size_t)(tb + r) * (NH * QHD) + h * QHD + cidx];
        if (cidx < NOPE) qn[r][cidx] = v;
        else             qp[r][cidx - NOPE] = v;
    }
    __syncthreads();
    // each thread owns one latent dim k for all 16 rows
    int k = tid;
    float acc[QTB];
    #pragma unroll
    for (int r = 0; r < QTB; r++) acc[r] = 0.f;
    const float* w = w_kc + (size_t)h * NOPE * KVLORA + k;
    for (int n = 0; n < NOPE; n++) {
        float wval = w[(size_t)n * KVLORA];
        #pragma unroll
        for (int r = 0; r < QTB; r++) acc[r] += qn[r][n] * wval;
    }
    #pragma unroll
    for (int r = 0; r < QTB; r++)
        qin[((size_t)(tb + r) * NH + h) * DQK + k] = f2bf(acc[r] * scale);
    // rope: 16 rows x 16 freqs = 256 threads
    int r = tid >> 4, fi = tid & 15;
    float pos = (float)positions[tb + r];
    float freq = powf(THETA, -(float)fi / 16.0f);
    float f = pos * freq;
    float c = cosf(f), s = sinf(f);
    float x1 = qp[r][fi], x2 = qp[r][16 + fi];
    ushort* orow = qin + ((size_t)(tb + r) * NH + h) * DQK;
    orow[KVLORA + fi]      = f2bf((x1 * c - x2 * s) * scale);
    orow[KVLORA + 16 + fi] = f2bf((x2 * c + x1 * s) * scale);
}

// ---------------- flash MFMA attention (r0 staging) + dedicated pbuf + fused w_vc ----------------
// pbuf is a DEDICATED region (verified correct in r1/r2): P rows are per-wave-private,
// so both P barriers vanish -> 2 barriers/iter instead of 4. VSTR 72->68 makes it fit
// exactly in 80 KiB (2 blocks/CU): PV-read banks stay balanced (8 lanes x 4B per bank
// = the 8-clk minimum), V-scatter b16 writes stay 2-lanes/bank (free).
#define KSTR 296
#define VSTR 68
#define PSTR 72
#define OSTR 264

__global__ __launch_bounds__(256, 2) void flash_attn(const ushort* __restrict__ qin,
                                                     const ushort* __restrict__ kin,
                                                     const ushort* __restrict__ w_vct,
                                                     ushort* __restrict__ o_bf) {
    __shared__ __align__(16) ushort lds[64 * KSTR + 256 * VSTR + 64 * PSTR];  // 81920 B
    ushort* krow = lds;                           // 64 x 296
    ushort* vt   = lds + 64 * KSTR;               // 256 x 68
    ushort* pbuf = vt + 256 * VSTR;               // 64 x 72 (dedicated, per-wave rows)

    const int tid  = threadIdx.x;
    const int lane = tid & 63;
    const int wv   = tid >> 6;
    const int col  = lane & 15;
    const int quad = lane >> 4;
    const int h    = blockIdx.y;
    const int qb   = ((int)gridDim.x - 1 - (int)blockIdx.x) * 64;

    bf16x8 qf[9];
    {
        const ushort* base = qin + ((size_t)(qb + wv * 16 + col) * NH + h) * DQK + quad * 8;
        #pragma unroll
        for (int k = 0; k < 9; k++) qf[k] = *(const bf16x8*)(base + k * 32);
    }

    f32x4 of[16];
    #pragma unroll
    for (int i = 0; i < 16; i++) of[i] = (f32x4){0.f, 0.f, 0.f, 0.f};
    float m_i[4] = {-1e30f, -1e30f, -1e30f, -1e30f};
    float l_i[4] = {0.f, 0.f, 0.f, 0.f};

    for (int s0 = 0; s0 <= qb; s0 += 64) {
        __syncthreads();
        {
            const ushort* src = kin + (size_t)(s0 + lane) * DQK;
            #pragma unroll
            for (int ci = 0; ci < 9; ci++) {
                int c = ci * 4 + wv;
                uint4 u = *(const uint4*)(src + c * 8);
                *(uint4*)(krow + lane * KSTR + c * 8) = u;
                if (c < 32) {
                    const ushort* up = (const ushort*)&u;
                    #pragma unroll
                    for (int j = 0; j < 8; j++)
                        vt[(c * 8 + j) * VSTR + lane] = up[j];
                }
            }
        }
        __syncthreads();
        f32x4 sf[4];
        #pragma unroll
        for (int tc = 0; tc < 4; tc++) sf[tc] = (f32x4){0.f, 0.f, 0.f, 0.f};
        #pragma unroll
        for (int k = 0; k < 9; k++) {
            #pragma unroll
            for (int tc = 0; tc < 4; tc++) {
                bf16x8 bf = *(const bf16x8*)(krow + (tc * 16 + col) * KSTR + k * 32 + quad * 8);
                sf[tc] = __builtin_amdgcn_mfma_f32_16x16x32_bf16(qf[k], bf, sf[tc], 0, 0, 0);
            }
        }
        if (s0 == qb) {
            #pragma unroll
            for (int tc = 0; tc < 4; tc++)
                #pragma unroll
                for (int r = 0; r < 4; r++)
                    if (tc * 16 + col > wv * 16 + quad * 4 + r) sf[tc][r] = -1e30f;
        }
        float mnew[4], alpha[4];
        #pragma unroll
        for (int r = 0; r < 4; r++) {
            float mx = fmaxf(fmaxf(sf[0][r], sf[1][r]), fmaxf(sf[2][r], sf[3][r]));
            mx = fmaxf(mx, __shfl_xor(mx, 1));
            mx = fmaxf(mx, __shfl_xor(mx, 2));
            mx = fmaxf(mx, __shfl_xor(mx, 4));
            mx = fmaxf(mx, __shfl_xor(mx, 8));
            mnew[r] = fmaxf(m_i[r], mx);
            alpha[r] = __expf(m_i[r] - mnew[r]);
            m_i[r] = mnew[r];
        }
        float rsum[4];
        #pragma unroll
        for (int r = 0; r < 4; r++) {
            float s = 0.f;
            #pragma unroll
            for (int tc = 0; tc < 4; tc++) {
                float p = __expf(sf[tc][r] - mnew[r]);
                sf[tc][r] = p;
                s += p;
            }
            s += __shfl_xor(s, 1);
            s += __shfl_xor(s, 2);
            s += __shfl_xor(s, 4);
            s += __shfl_xor(s, 8);
            rsum[r] = s;
        }
        #pragma unroll
        for (int r = 0; r < 4; r++) l_i[r] = l_i[r] * alpha[r] + rsum[r];
        #pragma unroll
        for (int i = 0; i < 16; i++)
            #pragma unroll
            for (int r = 0; r < 4; r++) of[i][r] *= alpha[r];
        // ---- P -> dedicated pbuf (per-wave-private rows: NO barriers) ----
        #pragma unroll
        for (int tc = 0; tc < 4; tc++)
            #pragma unroll
            for (int r = 0; r < 4; r++)
                pbuf[(wv * 16 + quad * 4 + r) * PSTR + tc * 16 + col] = f2bf(sf[tc][r]);
        bf16x8 pa[2];
        #pragma unroll
        for (int ks = 0; ks < 2; ks++)
            pa[ks] = *(const bf16x8*)(pbuf + (wv * 16 + col) * PSTR + ks * 32 + quad * 8);
        #pragma unroll
        for (int nt = 0; nt < 16; nt++) {
            #pragma unroll
            for (int ks = 0; ks < 2; ks++) {
                bf16x8 vb = *(const bf16x8*)(vt + (nt * 16 + col) * VSTR + ks * 32 + quad * 8);
                of[nt] = __builtin_amdgcn_mfma_f32_16x16x32_bf16(pa[ks], vb, of[nt], 0, 0, 0);
            }
        }
    }

    // ---------------- fused epilogue: o_bf[rows, h*64..] = (O/l) @ w_vc[h] ----------------
    __syncthreads();                       // all waves done with krow/vt
    ushort* obuf = lds;                    // 64 x OSTR (fits in krow region: 264 <= 296)
    ushort* wbuf = lds + 64 * KSTR;        // 64 x OSTR (fits in vt region: 16896 <= 17408)
    {
        float inv_l[4];
        #pragma unroll
        for (int r = 0; r < 4; r++) inv_l[r] = 1.0f / l_i[r];
        #pragma unroll
        for (int nt = 0; nt < 16; nt++)
            #pragma unroll
            for (int r = 0; r < 4; r++)
                obuf[(wv * 16 + quad * 4 + r) * OSTR + nt * 16 + col] = f2bf(of[nt][r] * inv_l[r]);
        // stage w_vct[h]: 64 rows x 256 k (32 KB), 8 x uint4 per thread, coalesced
        const ushort* wsrc = w_vct + (size_t)h * VDIM * KVLORA;
        #pragma unroll
        for (int i = 0; i < 8; i++) {
            int s = i * 256 + tid;
            int row = s >> 5, ch = s & 31;
            *(uint4*)(wbuf + row * OSTR + ch * 8) = *(const uint4*)(wsrc + (size_t)row * KVLORA + ch * 8);
        }
    }
    __syncthreads();
    f32x4 acc[4];
    #pragma unroll
    for (int j = 0; j < 4; j++) acc[j] = (f32x4){0.f, 0.f, 0.f, 0.f};
    #pragma unroll
    for (int ks = 0; ks < 8; ks++) {
        bf16x8 af = *(const bf16x8*)(obuf + (wv * 16 + col) * OSTR + ks * 32 + quad * 8);
        #pragma unroll
        for (int j = 0; j < 4; j++) {
            bf16x8 bw = *(const bf16x8*)(wbuf + (j * 16 + col) * OSTR + ks * 32 + quad * 8);
            acc[j] = __builtin_amdgcn_mfma_f32_16x16x32_bf16(af, bw, acc[j], 0, 0, 0);
        }
    }
    #pragma unroll
    for (int j = 0; j < 4; j++) {
        int gc = h * VDIM + j * 16 + col;
        #pragma unroll
        for (int r = 0; r < 4; r++)
            o_bf[(size_t)(qb + wv * 16 + quad * 4 + r) * HID + gc] = f2bf(acc[j][r]);
    }
}

extern "C" void kernel_launch(void* const* d_in, const int* in_sizes, int n_in,
                              void* d_out, int out_size, void* d_ws, size_t ws_size,
                              hipStream_t stream) {
    const int*   positions = (const int*)d_in[0];
    const float* hs    = (const float*)d_in[1];
    const float* w_qa  = (const float*)d_in[2];
    const float* g_qa  = (const float*)d_in[3];
    const float* w_qb  = (const float*)d_in[4];
    const float* w_kva = (const float*)d_in[5];
    const float* g_kva = (const float*)d_in[6];
    const float* w_kc  = (const float*)d_in[7];
    const float* w_vc  = (const float*)d_in[8];
    const float* w_o   = (const float*)d_in[9];
    float* out = (float*)d_out;

    float* ws    = (float*)d_ws;
    float* qa    = ws;                               // T*768
    float* q     = qa    + (size_t)TT * QLORA;       // T*3840
    float* kin   = q     + (size_t)TT * NH * QHD;    // T*288
    ushort* ub     = (ushort*)(kin + (size_t)TT * DQK);
    ushort* hs_bf  = ub;                             // T*2560
    ushort* qa_bf  = hs_bf  + (size_t)TT * HID;      // T*768
    ushort* o_bf   = qa_bf  + (size_t)TT * QLORA;    // T*2560
    ushort* kin_bf = o_bf   + (size_t)TT * HID;      // T*288
    ushort* qin_bf = kin_bf + (size_t)TT * DQK;      // T*40*288
    ushort* w_qa_t  = qin_bf + (size_t)TT * NH * DQK;       // 768*2560
    ushort* w_qb_t  = w_qa_t + (size_t)QLORA * HID;         // 3840*768
    ushort* w_kva_t = w_qb_t + (size_t)(NH * QHD) * QLORA;  // 288*2560
    ushort* w_o_t   = w_kva_t + (size_t)DQK * HID;          // 2560*2560
    ushort* w_vc_t  = w_o_t + (size_t)HID * HID;            // 40*64*256

    // ---- casts / transposes (independent of each other) ----
    cast_bf16<<<(TT * HID) / 1024, 256, 0, stream>>>(hs, hs_bf, TT * HID);
    transpose_cast<<<dim3(QLORA / 32, HID / 32), 256, 0, stream>>>(w_qa, w_qa_t, HID, QLORA);
    transpose_cast<<<dim3((NH * QHD) / 32, QLORA / 32), 256, 0, stream>>>(w_qb, w_qb_t, QLORA, NH * QHD);
    transpose_cast<<<dim3(DQK / 32, HID / 32), 256, 0, stream>>>(w_kva, w_kva_t, HID, DQK);
    transpose_cast<<<dim3(HID / 32, HID / 32), 256, 0, stream>>>(w_o, w_o_t, HID, HID);
    transpose_vc<<<dim3(VDIM / 32, KVLORA / 32, NH), 256, 0, stream>>>(w_vc, w_vc_t);

    // 1. qa = hs @ w_qa (MFMA, 128x64 tile: N=768 -> 192 blocks); RMS -> qa_bf
    gemm_bf16_n64<<<dim3(QLORA / 64, TT / 128), 256, 0, stream>>>(hs_bf, w_qa_t, qa, TT, QLORA, HID);
    rms_qa<<<TT, 256, 0, stream>>>(qa, g_qa, qa_bf);
    // 2. q = qa @ w_qb (MFMA)
    gemm_bf16<<<dim3((NH * QHD) / 128, TT / 128), 256, 0, stream>>>(qa_bf, w_qb_t, q, TT, NH * QHD, QLORA);
    // 3. kin = hs @ w_kva (MFMA, 128x64 tile: N=288 -> 80 blocks); RMS+RoPE -> kin_bf
    gemm_bf16_n64<<<dim3((DQK + 63) / 64, TT / 128), 256, 0, stream>>>(hs_bf, w_kva_t, kin, TT, DQK, HID);
    kin_post<<<TT, 256, 0, stream>>>(kin, g_kva, positions, kin_bf);
    // 4. qin_bf = [q_nope @ w_kc[h] | rope(q_pe)] * scale
    build_qin<<<dim3(TT / QTB, NH), 256, 0, stream>>>(q, w_kc, positions, qin_bf);
    // 5. flash MFMA attention with fused w_vc projection -> o_bf directly
    flash_attn<<<dim3(TT / 64, NH), 256, 0, stream>>>(qin_bf, kin_bf, w_vc_t, o_bf);
    // 6. out = o_bf @ w_o (MFMA)
    gemm_bf16<<<dim3(HID / 128, TT / 128), 256, 0, stream>>>(o_bf, w_o_t, out, TT, HID, HID);
}

// Round 13
// 735.073 us; speedup vs baseline: 1.6863x; 1.6863x over previous
//
#include <hip/hip_runtime.h>
#include <hip/hip_bf16.h>
#include <math.h>

#define TT 2048
#define HID 2560
#define NH 40
#define NOPE 64
#define ROPE 32
#define VDIM 64
#define QLORA 768
#define KVLORA 256
#define DQK 288            // KVLORA + ROPE
#define QHD 96             // NOPE + ROPE
#define NQK 1056           // QLORA + DQK (fused gemm N)
#define EPS 1e-5f
#define THETA 10000.0f

typedef __attribute__((ext_vector_type(8))) short bf16x8;
typedef __attribute__((ext_vector_type(4))) float f32x4;
typedef __attribute__((address_space(1))) const void* gas_t;
typedef __attribute__((address_space(3))) void* las_t;

static __device__ __forceinline__ ushort f2bf(float x) {
    __hip_bfloat16 b = __float2bfloat16(x);
    return *reinterpret_cast<ushort*>(&b);
}

// ---------------- flat fp32 -> bf16 cast ----------------
__global__ __launch_bounds__(256) void cast_bf16(const float* __restrict__ x,
                                                 ushort* __restrict__ y, int n) {
    int i = (blockIdx.x * 256 + threadIdx.x) * 4;
    if (i + 3 < n) {
        float4 v = *(const float4*)(x + i);
        y[i]     = f2bf(v.x);
        y[i + 1] = f2bf(v.y);
        y[i + 2] = f2bf(v.z);
        y[i + 3] = f2bf(v.w);
    }
}

// ------------- transpose + cast: w (K x N fp32) -> wt (N x K bf16) -------------
__global__ __launch_bounds__(256) void transpose_cast(const float* __restrict__ w,
                                                      ushort* __restrict__ wt,
                                                      int K, int N) {
    __shared__ float tile[32][33];
    int bn = blockIdx.x * 32, bk = blockIdx.y * 32;
    int tx = threadIdx.x % 32, ty = threadIdx.x / 32;   // 32 x 8
    #pragma unroll
    for (int i = 0; i < 32; i += 8) {
        int k = bk + ty + i, n = bn + tx;
        if (k < K && n < N) tile[ty + i][tx] = w[(size_t)k * N + n];
    }
    __syncthreads();
    #pragma unroll
    for (int i = 0; i < 32; i += 8) {
        int n = bn + ty + i, k = bk + tx;
        if (n < N && k < K) wt[(size_t)n * K + k] = f2bf(tile[tx][ty + i]);
    }
}

// ---- per-head transpose: w_vc (H, K=256, V=64) fp32 -> w_vct (H, V=64, K=256) bf16 ----
__global__ __launch_bounds__(256) void transpose_vc(const float* __restrict__ w,
                                                    ushort* __restrict__ wt) {
    __shared__ float tile[32][33];
    int h = blockIdx.z;
    const float* src = w + (size_t)h * KVLORA * VDIM;
    ushort* dst = wt + (size_t)h * VDIM * KVLORA;
    int bn = blockIdx.x * 32, bk = blockIdx.y * 32;     // n over V, k over KVLORA
    int tx = threadIdx.x % 32, ty = threadIdx.x / 32;
    #pragma unroll
    for (int i = 0; i < 32; i += 8)
        tile[ty + i][tx] = src[(size_t)(bk + ty + i) * VDIM + bn + tx];
    __syncthreads();
    #pragma unroll
    for (int i = 0; i < 32; i += 8)
        dst[(size_t)(bn + ty + i) * KVLORA + bk + tx] = f2bf(tile[tx][ty + i]);
}

// ------- bf16 MFMA GEMM (m97 structure): C(MxN,f32) = A(MxK,bf16) @ Bt(NxK,bf16)^T -------
__global__ __launch_bounds__(256, 2) void gemm_bf16(const ushort* __restrict__ A,
                                                    const ushort* __restrict__ Bt,
                                                    float* __restrict__ C,
                                                    int M, int N, int K) {
    __shared__ ushort As[128 * 32];
    __shared__ ushort Bs[128 * 32];
    const int tid  = threadIdx.x;
    const int lane = tid & 63;
    const int wv   = tid >> 6;
    const int col  = lane & 15;
    const int quad = lane >> 4;
    const int m0 = blockIdx.y * 128, n0 = blockIdx.x * 128;
    const int wr = (wv >> 1) * 64, wc = (wv & 1) * 64;

    f32x4 acc[4][4];
    #pragma unroll
    for (int i = 0; i < 4; i++)
        #pragma unroll
        for (int j = 0; j < 4; j++) acc[i][j] = (f32x4){0.f, 0.f, 0.f, 0.f};

    for (int k0 = 0; k0 < K; k0 += 32) {
        #pragma unroll
        for (int j = 0; j < 2; j++) {
            int slot = wv * 128 + j * 64 + lane;     // 0..511
            int row  = slot >> 2;
            int ch   = slot & 3;
            const ushort* ga = A + (size_t)(m0 + row) * K + k0 + ch * 8;
            __builtin_amdgcn_global_load_lds((gas_t)ga, (las_t)(As + slot * 8), 16, 0, 0);
            int brow = n0 + row; if (brow >= N) brow = N - 1;   // clamp (edge tiles)
            const ushort* gb = Bt + (size_t)brow * K + k0 + ch * 8;
            __builtin_amdgcn_global_load_lds((gas_t)gb, (las_t)(Bs + slot * 8), 16, 0, 0);
        }
        __syncthreads();
        bf16x8 af[4], bfr[4];
        #pragma unroll
        for (int i = 0; i < 4; i++)
            af[i] = *(const bf16x8*)(As + (wr + i * 16 + col) * 32 + quad * 8);
        #pragma unroll
        for (int j = 0; j < 4; j++)
            bfr[j] = *(const bf16x8*)(Bs + (wc + j * 16 + col) * 32 + quad * 8);
        #pragma unroll
        for (int i = 0; i < 4; i++)
            #pragma unroll
            for (int j = 0; j < 4; j++)
                acc[i][j] = __builtin_amdgcn_mfma_f32_16x16x32_bf16(af[i], bfr[j], acc[i][j], 0, 0, 0);
        __syncthreads();
    }
    #pragma unroll
    for (int i = 0; i < 4; i++) {
        int gr = m0 + wr + i * 16 + quad * 4;
        #pragma unroll
        for (int j = 0; j < 4; j++) {
            int gc = n0 + wc + j * 16 + col;
            if (gc < N) {
                #pragma unroll
                for (int r = 0; r < 4; r++)
                    C[(size_t)(gr + r) * N + gc] = acc[i][j][r];
            }
        }
    }
}

// ------- fused narrow-N GEMM: hs_bf @ [w_qa_t | w_kva_t]^T -> qa (cols<768) / kin (cols>=768) -------
__global__ __launch_bounds__(256, 4) void gemm_qkva(const ushort* __restrict__ A,
                                                    const ushort* __restrict__ Bt,
                                                    float* __restrict__ qa,
                                                    float* __restrict__ kin,
                                                    int K) {
    __shared__ ushort As[128 * 32];
    __shared__ ushort Bs[64 * 32];
    const int tid  = threadIdx.x;
    const int lane = tid & 63;
    const int wv   = tid >> 6;
    const int col  = lane & 15;
    const int quad = lane >> 4;
    const int m0 = blockIdx.y * 128, n0 = blockIdx.x * 64;
    const int wr = wv * 32;

    f32x4 acc[2][4];
    #pragma unroll
    for (int i = 0; i < 2; i++)
        #pragma unroll
        for (int j = 0; j < 4; j++) acc[i][j] = (f32x4){0.f, 0.f, 0.f, 0.f};

    for (int k0 = 0; k0 < K; k0 += 32) {
        #pragma unroll
        for (int j = 0; j < 2; j++) {                // A: 512 slots, 2/thread
            int slot = j * 256 + tid;
            int row  = slot >> 2;
            int ch   = slot & 3;
            const ushort* ga = A + (size_t)(m0 + row) * K + k0 + ch * 8;
            __builtin_amdgcn_global_load_lds((gas_t)ga, (las_t)(As + slot * 8), 16, 0, 0);
        }
        {                                            // B: 256 slots, 1/thread
            int row = tid >> 2;
            int ch  = tid & 3;
            int brow = n0 + row; if (brow >= NQK) brow = NQK - 1;
            const ushort* gb = Bt + (size_t)brow * K + k0 + ch * 8;
            __builtin_amdgcn_global_load_lds((gas_t)gb, (las_t)(Bs + tid * 8), 16, 0, 0);
        }
        __syncthreads();
        bf16x8 af[2], bfr[4];
        #pragma unroll
        for (int i = 0; i < 2; i++)
            af[i] = *(const bf16x8*)(As + (wr + i * 16 + col) * 32 + quad * 8);
        #pragma unroll
        for (int j = 0; j < 4; j++)
            bfr[j] = *(const bf16x8*)(Bs + (j * 16 + col) * 32 + quad * 8);
        #pragma unroll
        for (int i = 0; i < 2; i++)
            #pragma unroll
            for (int j = 0; j < 4; j++)
                acc[i][j] = __builtin_amdgcn_mfma_f32_16x16x32_bf16(af[i], bfr[j], acc[i][j], 0, 0, 0);
        __syncthreads();
    }
    #pragma unroll
    for (int i = 0; i < 2; i++) {
        int gr = m0 + wr + i * 16 + quad * 4;
        #pragma unroll
        for (int j = 0; j < 4; j++) {
            int gc = n0 + j * 16 + col;
            if (gc < QLORA) {
                #pragma unroll
                for (int r = 0; r < 4; r++)
                    qa[(size_t)(gr + r) * QLORA + gc] = acc[i][j][r];
            } else if (gc < NQK) {
                int kc = gc - QLORA;
                #pragma unroll
                for (int r = 0; r < 4; r++)
                    kin[(size_t)(gr + r) * DQK + kc] = acc[i][j][r];
            }
        }
    }
}

// ---------------- RMS norm: fp32 in, bf16 out ----------------
__global__ __launch_bounds__(256) void rms_qa(const float* __restrict__ x,
                                              const float* __restrict__ g,
                                              ushort* __restrict__ y) {
    int t = blockIdx.x, tid = threadIdx.x;
    __shared__ float red[256];
    __shared__ float s_inv;
    const float* row = x + (size_t)t * QLORA;
    float ss = 0.f;
    for (int i = tid; i < QLORA; i += 256) { float v = row[i]; ss += v * v; }
    red[tid] = ss; __syncthreads();
    for (int s = 128; s > 0; s >>= 1) { if (tid < s) red[tid] += red[tid + s]; __syncthreads(); }
    if (tid == 0) s_inv = rsqrtf(red[0] / (float)QLORA + EPS);
    __syncthreads();
    float si = s_inv;
    ushort* orow = y + (size_t)t * QLORA;
    for (int i = tid; i < QLORA; i += 256) orow[i] = f2bf(row[i] * si * g[i]);
}

// ------- latent post: RMS first 256, RoPE last 32 -> bf16 kin_bf (T x 288) -------
__global__ __launch_bounds__(256) void kin_post(const float* __restrict__ kin,
                                                const float* __restrict__ g,
                                                const int* __restrict__ positions,
                                                ushort* __restrict__ kin_bf) {
    int t = blockIdx.x, tid = threadIdx.x;
    __shared__ float red[256];
    __shared__ float s_inv;
    const float* row = kin + (size_t)t * DQK;
    float v = row[tid];
    red[tid] = v * v; __syncthreads();
    for (int s = 128; s > 0; s >>= 1) { if (tid < s) red[tid] += red[tid + s]; __syncthreads(); }
    if (tid == 0) s_inv = rsqrtf(red[0] / (float)KVLORA + EPS);
    __syncthreads();
    ushort* orow = kin_bf + (size_t)t * DQK;
    orow[tid] = f2bf(v * s_inv * g[tid]);
    if (tid < 16) {
        float pos = (float)positions[t];
        float freq = powf(THETA, -(float)tid / 16.0f);
        float f = pos * freq;
        float c = cosf(f), s = sinf(f);
        float x1 = row[KVLORA + tid], x2 = row[KVLORA + 16 + tid];
        orow[KVLORA + tid]      = f2bf(x1 * c - x2 * s);
        orow[KVLORA + 16 + tid] = f2bf(x2 * c + x1 * s);
    }
}

// --- q_in build (tiled: 16 t-rows per block, w_kc[h] read once per block) ---
#define QTB 16
__global__ __launch_bounds__(256) void build_qin(const float* __restrict__ q,
                                                 const float* __restrict__ w_kc,
                                                 const int* __restrict__ positions,
                                                 ushort* __restrict__ qin) {
    int tb = blockIdx.x * QTB, h = blockIdx.y, tid = threadIdx.x;
    const float scale = 0.10206207261596577f;   // 1/sqrt(96), folded into Q
    __shared__ float qn[QTB][NOPE];
    __shared__ float qp[QTB][ROPE];
    // load 16 q rows (96 floats each)
    for (int i = tid; i < QTB * QHD; i += 256) {
        int r = i / QHD, cidx = i % QHD;
        float v = q[(size_t)(tb + r) * (NH * QHD) + h * QHD + cidx];
        if (cidx < NOPE) qn[r][cidx] = v;
        else             qp[r][cidx - NOPE] = v;
    }
    __syncthreads();
    // each thread owns one latent dim k for all 16 rows
    int k = tid;
    float acc[QTB];
    #pragma unroll
    for (int r = 0; r < QTB; r++) acc[r] = 0.f;
    const float* w = w_kc + (size_t)h * NOPE * KVLORA + k;
    for (int n = 0; n < NOPE; n++) {
        float wval = w[(size_t)n * KVLORA];
        #pragma unroll
        for (int r = 0; r < QTB; r++) acc[r] += qn[r][n] * wval;
    }
    #pragma unroll
    for (int r = 0; r < QTB; r++)
        qin[((size_t)(tb + r) * NH + h) * DQK + k] = f2bf(acc[r] * scale);
    // rope: 16 rows x 16 freqs = 256 threads
    int r = tid >> 4, fi = tid & 15;
    float pos = (float)positions[tb + r];
    float freq = powf(THETA, -(float)fi / 16.0f);
    float f = pos * freq;
    float c = cosf(f), s = sinf(f);
    float x1 = qp[r][fi], x2 = qp[r][16 + fi];
    ushort* orow = qin + ((size_t)(tb + r) * NH + h) * DQK;
    orow[KVLORA + fi]      = f2bf((x1 * c - x2 * s) * scale);
    orow[KVLORA + 16 + fi] = f2bf((x2 * c + x1 * s) * scale);
}

// ---------------- flash MFMA attention (r10 structure, 3 barriers/iter) + fused w_vc ----------------
// pbuf aliases krow (LDS stays 74752 B -> 2 blocks/CU; r12's 81920 dropped residency to 1).
// The barrier AFTER the P-write is removed: wave w writes pbuf rows [16w,16w+16) and reads
// pa from exactly those rows (disjoint 2304-B ranges per wave; own-wave write->read ordered
// by lgkmcnt). The barrier BEFORE the P-write stays (P clobbers krow bytes other waves read
// during QK^T). 4 -> 3 barriers per iteration.
#define KSTR 296
#define VSTR 72
#define PSTR 72
#define OSTR 264

__global__ __launch_bounds__(256, 2) void flash_attn(const ushort* __restrict__ qin,
                                                     const ushort* __restrict__ kin,
                                                     const ushort* __restrict__ w_vct,
                                                     ushort* __restrict__ o_bf) {
    __shared__ __align__(16) ushort lds[64 * KSTR + 256 * VSTR];
    ushort* krow = lds;
    ushort* vt   = lds + 64 * KSTR;
    ushort* pbuf = lds;                 // alias of krow region (per-wave-private rows)

    const int tid  = threadIdx.x;
    const int lane = tid & 63;
    const int wv   = tid >> 6;
    const int col  = lane & 15;
    const int quad = lane >> 4;
    const int h    = blockIdx.y;
    const int qb   = ((int)gridDim.x - 1 - (int)blockIdx.x) * 64;

    bf16x8 qf[9];
    {
        const ushort* base = qin + ((size_t)(qb + wv * 16 + col) * NH + h) * DQK + quad * 8;
        #pragma unroll
        for (int k = 0; k < 9; k++) qf[k] = *(const bf16x8*)(base + k * 32);
    }

    f32x4 of[16];
    #pragma unroll
    for (int i = 0; i < 16; i++) of[i] = (f32x4){0.f, 0.f, 0.f, 0.f};
    float m_i[4] = {-1e30f, -1e30f, -1e30f, -1e30f};
    float l_i[4] = {0.f, 0.f, 0.f, 0.f};

    for (int s0 = 0; s0 <= qb; s0 += 64) {
        __syncthreads();
        {
            const ushort* src = kin + (size_t)(s0 + lane) * DQK;
            #pragma unroll
            for (int ci = 0; ci < 9; ci++) {
                int c = ci * 4 + wv;
                uint4 u = *(const uint4*)(src + c * 8);
                *(uint4*)(krow + lane * KSTR + c * 8) = u;
                if (c < 32) {
                    const ushort* up = (const ushort*)&u;
                    #pragma unroll
                    for (int j = 0; j < 8; j++)
                        vt[(c * 8 + j) * VSTR + lane] = up[j];
                }
            }
        }
        __syncthreads();
        f32x4 sf[4];
        #pragma unroll
        for (int tc = 0; tc < 4; tc++) sf[tc] = (f32x4){0.f, 0.f, 0.f, 0.f};
        #pragma unroll
        for (int k = 0; k < 9; k++) {
            #pragma unroll
            for (int tc = 0; tc < 4; tc++) {
                bf16x8 bf = *(const bf16x8*)(krow + (tc * 16 + col) * KSTR + k * 32 + quad * 8);
                sf[tc] = __builtin_amdgcn_mfma_f32_16x16x32_bf16(qf[k], bf, sf[tc], 0, 0, 0);
            }
        }
        if (s0 == qb) {
            #pragma unroll
            for (int tc = 0; tc < 4; tc++)
                #pragma unroll
                for (int r = 0; r < 4; r++)
                    if (tc * 16 + col > wv * 16 + quad * 4 + r) sf[tc][r] = -1e30f;
        }
        float mnew[4], alpha[4];
        #pragma unroll
        for (int r = 0; r < 4; r++) {
            float mx = fmaxf(fmaxf(sf[0][r], sf[1][r]), fmaxf(sf[2][r], sf[3][r]));
            mx = fmaxf(mx, __shfl_xor(mx, 1));
            mx = fmaxf(mx, __shfl_xor(mx, 2));
            mx = fmaxf(mx, __shfl_xor(mx, 4));
            mx = fmaxf(mx, __shfl_xor(mx, 8));
            mnew[r] = fmaxf(m_i[r], mx);
            alpha[r] = __expf(m_i[r] - mnew[r]);
            m_i[r] = mnew[r];
        }
        float rsum[4];
        #pragma unroll
        for (int r = 0; r < 4; r++) {
            float s = 0.f;
            #pragma unroll
            for (int tc = 0; tc < 4; tc++) {
                float p = __expf(sf[tc][r] - mnew[r]);
                sf[tc][r] = p;
                s += p;
            }
            s += __shfl_xor(s, 1);
            s += __shfl_xor(s, 2);
            s += __shfl_xor(s, 4);
            s += __shfl_xor(s, 8);
            rsum[r] = s;
        }
        #pragma unroll
        for (int r = 0; r < 4; r++) l_i[r] = l_i[r] * alpha[r] + rsum[r];
        #pragma unroll
        for (int i = 0; i < 16; i++)
            #pragma unroll
            for (int r = 0; r < 4; r++) of[i][r] *= alpha[r];
        __syncthreads();                     // all waves done reading krow (QK^T) before P clobbers it
        #pragma unroll
        for (int tc = 0; tc < 4; tc++)
            #pragma unroll
            for (int r = 0; r < 4; r++)
                pbuf[(wv * 16 + quad * 4 + r) * PSTR + tc * 16 + col] = f2bf(sf[tc][r]);
        // no barrier: pa reads only this wave's own P rows (lgkmcnt orders write->read)
        bf16x8 pa[2];
        #pragma unroll
        for (int ks = 0; ks < 2; ks++)
            pa[ks] = *(const bf16x8*)(pbuf + (wv * 16 + col) * PSTR + ks * 32 + quad * 8);
        #pragma unroll
        for (int nt = 0; nt < 16; nt++) {
            #pragma unroll
            for (int ks = 0; ks < 2; ks++) {
                bf16x8 vb = *(const bf16x8*)(vt + (nt * 16 + col) * VSTR + ks * 32 + quad * 8);
                of[nt] = __builtin_amdgcn_mfma_f32_16x16x32_bf16(pa[ks], vb, of[nt], 0, 0, 0);
            }
        }
    }

    // ---------------- fused epilogue: o_bf[rows, h*64..] = (O/l) @ w_vc[h] ----------------
    __syncthreads();                       // all waves done with krow/vt
    ushort* obuf = lds;                    // 64 x OSTR (fits in krow region: 264 <= 296)
    ushort* wbuf = lds + 64 * KSTR;        // 64 x OSTR (fits in vt region)
    {
        float inv_l[4];
        #pragma unroll
        for (int r = 0; r < 4; r++) inv_l[r] = 1.0f / l_i[r];
        #pragma unroll
        for (int nt = 0; nt < 16; nt++)
            #pragma unroll
            for (int r = 0; r < 4; r++)
                obuf[(wv * 16 + quad * 4 + r) * OSTR + nt * 16 + col] = f2bf(of[nt][r] * inv_l[r]);
        // stage w_vct[h]: 64 rows x 256 k (32 KB), 8 x uint4 per thread, coalesced
        const ushort* wsrc = w_vct + (size_t)h * VDIM * KVLORA;
        #pragma unroll
        for (int i = 0; i < 8; i++) {
            int s = i * 256 + tid;
            int row = s >> 5, ch = s & 31;
            *(uint4*)(wbuf + row * OSTR + ch * 8) = *(const uint4*)(wsrc + (size_t)row * KVLORA + ch * 8);
        }
    }
    __syncthreads();
    f32x4 acc[4];
    #pragma unroll
    for (int j = 0; j < 4; j++) acc[j] = (f32x4){0.f, 0.f, 0.f, 0.f};
    #pragma unroll
    for (int ks = 0; ks < 8; ks++) {
        bf16x8 af = *(const bf16x8*)(obuf + (wv * 16 + col) * OSTR + ks * 32 + quad * 8);
        #pragma unroll
        for (int j = 0; j < 4; j++) {
            bf16x8 bw = *(const bf16x8*)(wbuf + (j * 16 + col) * OSTR + ks * 32 + quad * 8);
            acc[j] = __builtin_amdgcn_mfma_f32_16x16x32_bf16(af, bw, acc[j], 0, 0, 0);
        }
    }
    #pragma unroll
    for (int j = 0; j < 4; j++) {
        int gc = h * VDIM + j * 16 + col;
        #pragma unroll
        for (int r = 0; r < 4; r++)
            o_bf[(size_t)(qb + wv * 16 + quad * 4 + r) * HID + gc] = f2bf(acc[j][r]);
    }
}

extern "C" void kernel_launch(void* const* d_in, const int* in_sizes, int n_in,
                              void* d_out, int out_size, void* d_ws, size_t ws_size,
                              hipStream_t stream) {
    const int*   positions = (const int*)d_in[0];
    const float* hs    = (const float*)d_in[1];
    const float* w_qa  = (const float*)d_in[2];
    const float* g_qa  = (const float*)d_in[3];
    const float* w_qb  = (const float*)d_in[4];
    const float* w_kva = (const float*)d_in[5];
    const float* g_kva = (const float*)d_in[6];
    const float* w_kc  = (const float*)d_in[7];
    const float* w_vc  = (const float*)d_in[8];
    const float* w_o   = (const float*)d_in[9];
    float* out = (float*)d_out;

    float* ws    = (float*)d_ws;
    float* qa    = ws;                               // T*768
    float* q     = qa    + (size_t)TT * QLORA;       // T*3840
    float* kin   = q     + (size_t)TT * NH * QHD;    // T*288
    ushort* ub     = (ushort*)(kin + (size_t)TT * DQK);
    ushort* hs_bf  = ub;                             // T*2560
    ushort* qa_bf  = hs_bf  + (size_t)TT * HID;      // T*768
    ushort* o_bf   = qa_bf  + (size_t)TT * QLORA;    // T*2560
    ushort* kin_bf = o_bf   + (size_t)TT * HID;      // T*288
    ushort* qin_bf = kin_bf + (size_t)TT * DQK;      // T*40*288
    ushort* w_qk_t  = qin_bf + (size_t)TT * NH * DQK;       // 1056*2560 (w_qa_t | w_kva_t)
    ushort* w_qb_t  = w_qk_t + (size_t)NQK * HID;           // 3840*768
    ushort* w_o_t   = w_qb_t + (size_t)(NH * QHD) * QLORA;  // 2560*2560
    ushort* w_vc_t  = w_o_t + (size_t)HID * HID;            // 40*64*256

    // ---- casts / transposes (independent of each other) ----
    cast_bf16<<<(TT * HID) / 1024, 256, 0, stream>>>(hs, hs_bf, TT * HID);
    transpose_cast<<<dim3(QLORA / 32, HID / 32), 256, 0, stream>>>(w_qa, w_qk_t, HID, QLORA);
    transpose_cast<<<dim3(DQK / 32, HID / 32), 256, 0, stream>>>(w_kva, w_qk_t + (size_t)QLORA * HID, HID, DQK);
    transpose_cast<<<dim3((NH * QHD) / 32, QLORA / 32), 256, 0, stream>>>(w_qb, w_qb_t, QLORA, NH * QHD);
    transpose_cast<<<dim3(HID / 32, HID / 32), 256, 0, stream>>>(w_o, w_o_t, HID, HID);
    transpose_vc<<<dim3(VDIM / 32, KVLORA / 32, NH), 256, 0, stream>>>(w_vc, w_vc_t);

    // 1+3 fused: [qa | kin] = hs @ [w_qa | w_kva]  (N=1056, 17x16=272 blocks)
    gemm_qkva<<<dim3((NQK + 63) / 64, TT / 128), 256, 0, stream>>>(hs_bf, w_qk_t, qa, kin, HID);
    rms_qa<<<TT, 256, 0, stream>>>(qa, g_qa, qa_bf);
    kin_post<<<TT, 256, 0, stream>>>(kin, g_kva, positions, kin_bf);
    // 2. q = qa @ w_qb (MFMA)
    gemm_bf16<<<dim3((NH * QHD) / 128, TT / 128), 256, 0, stream>>>(qa_bf, w_qb_t, q, TT, NH * QHD, QLORA);
    // 4. qin_bf = [q_nope @ w_kc[h] | rope(q_pe)] * scale
    build_qin<<<dim3(TT / QTB, NH), 256, 0, stream>>>(q, w_kc, positions, qin_bf);
    // 5. flash MFMA attention with fused w_vc projection -> o_bf directly
    flash_attn<<<dim3(TT / 64, NH), 256, 0, stream>>>(qin_bf, kin_bf, w_vc_t, o_bf);
    // 6. out = o_bf @ w_o (MFMA)
    gemm_bf16<<<dim3(HID / 128, TT / 128), 256, 0, stream>>>(o_bf, w_o_t, out, TT, HID, HID);
}

// Round 14
// 713.838 us; speedup vs baseline: 1.7364x; 1.0297x over previous
//
#include <hip/hip_runtime.h>
#include <hip/hip_bf16.h>
#include <math.h>

#define TT 2048
#define HID 2560
#define NH 40
#define NOPE 64
#define ROPE 32
#define VDIM 64
#define QLORA 768
#define KVLORA 256
#define DQK 288            // KVLORA + ROPE
#define QHD 96             // NOPE + ROPE
#define NQK 1056           // QLORA + DQK (fused gemm N)
#define EPS 1e-5f
#define THETA 10000.0f

typedef __attribute__((ext_vector_type(8))) short bf16x8;
typedef __attribute__((ext_vector_type(4))) float f32x4;
typedef __attribute__((address_space(1))) const void* gas_t;
typedef __attribute__((address_space(3))) void* las_t;

static __device__ __forceinline__ ushort f2bf(float x) {
    __hip_bfloat16 b = __float2bfloat16(x);
    return *reinterpret_cast<ushort*>(&b);
}

// ---------------- fused preprocessing: hs cast + all weight transposes ----------------
// One launch replaces 6. Flat block ranges; per-range code identical to the verified
// standalone kernels (all dims are multiples of 32 -> no bounds checks needed).
#define CAST_BLKS (TT * HID / 1024)                    // 5120
#define TQA_BLKS  ((QLORA / 32) * (HID / 32))          // 1920
#define TKVA_BLKS ((DQK / 32) * (HID / 32))            // 720
#define TQB_BLKS  ((NH * QHD / 32) * (QLORA / 32))     // 2880
#define TWO_BLKS  ((HID / 32) * (HID / 32))            // 6400
#define TVC_BLKS  ((VDIM / 32) * (KVLORA / 32) * NH)   // 640
#define PREP_BLKS (CAST_BLKS + TQA_BLKS + TKVA_BLKS + TQB_BLKS + TWO_BLKS + TVC_BLKS)

__global__ __launch_bounds__(256) void prep_all(const float* __restrict__ hs,
                                                ushort* __restrict__ hs_bf,
                                                const float* __restrict__ w_qa,
                                                const float* __restrict__ w_kva,
                                                const float* __restrict__ w_qb,
                                                const float* __restrict__ w_o,
                                                const float* __restrict__ w_vc,
                                                ushort* __restrict__ w_qk_t,
                                                ushort* __restrict__ w_qb_t,
                                                ushort* __restrict__ w_o_t,
                                                ushort* __restrict__ w_vc_t) {
    __shared__ float tile[32][33];
    int b = blockIdx.x, tid = threadIdx.x;

    if (b < CAST_BLKS) {                       // ---- hs fp32 -> bf16 ----
        int i = (b * 256 + tid) * 4;
        float4 v = *(const float4*)(hs + i);
        hs_bf[i]     = f2bf(v.x);
        hs_bf[i + 1] = f2bf(v.y);
        hs_bf[i + 2] = f2bf(v.z);
        hs_bf[i + 3] = f2bf(v.w);
        return;
    }
    b -= CAST_BLKS;

    const float* src; ushort* dst; int K, N, bx, by;
    if (b < TQA_BLKS) {                        // w_qa (2560x768) -> w_qk_t rows [0,768)
        src = w_qa; dst = w_qk_t; K = HID; N = QLORA;
        bx = b % (QLORA / 32); by = b / (QLORA / 32);
    } else if ((b -= TQA_BLKS) < TKVA_BLKS) {  // w_kva (2560x288) -> w_qk_t rows [768,1056)
        src = w_kva; dst = w_qk_t + (size_t)QLORA * HID; K = HID; N = DQK;
        bx = b % (DQK / 32); by = b / (DQK / 32);
    } else if ((b -= TKVA_BLKS) < TQB_BLKS) {  // w_qb (768x3840) -> w_qb_t
        src = w_qb; dst = w_qb_t; K = QLORA; N = NH * QHD;
        bx = b % (NH * QHD / 32); by = b / (NH * QHD / 32);
    } else if ((b -= TQB_BLKS) < TWO_BLKS) {   // w_o (2560x2560) -> w_o_t
        src = w_o; dst = w_o_t; K = HID; N = HID;
        bx = b % (HID / 32); by = b / (HID / 32);
    } else {                                   // w_vc per-head (256x64) -> w_vc_t (64x256)
        b -= TWO_BLKS;
        int h = b / ((VDIM / 32) * (KVLORA / 32));
        int lb = b % ((VDIM / 32) * (KVLORA / 32));
        src = w_vc + (size_t)h * KVLORA * VDIM;
        dst = w_vc_t + (size_t)h * VDIM * KVLORA;
        K = KVLORA; N = VDIM;
        bx = lb % (VDIM / 32); by = lb / (VDIM / 32);
    }

    int bn = bx * 32, bk = by * 32;
    int tx = tid & 31, ty = tid >> 5;          // 32 x 8
    #pragma unroll
    for (int i = 0; i < 32; i += 8)
        tile[ty + i][tx] = src[(size_t)(bk + ty + i) * N + bn + tx];
    __syncthreads();
    #pragma unroll
    for (int i = 0; i < 32; i += 8)
        dst[(size_t)(bn + ty + i) * K + bk + tx] = f2bf(tile[tx][ty + i]);
}

// ------- bf16 MFMA GEMM (m97 structure): C(MxN,f32) = A(MxK,bf16) @ Bt(NxK,bf16)^T -------
__global__ __launch_bounds__(256, 2) void gemm_bf16(const ushort* __restrict__ A,
                                                    const ushort* __restrict__ Bt,
                                                    float* __restrict__ C,
                                                    int M, int N, int K) {
    __shared__ ushort As[128 * 32];
    __shared__ ushort Bs[128 * 32];
    const int tid  = threadIdx.x;
    const int lane = tid & 63;
    const int wv   = tid >> 6;
    const int col  = lane & 15;
    const int quad = lane >> 4;
    const int m0 = blockIdx.y * 128, n0 = blockIdx.x * 128;
    const int wr = (wv >> 1) * 64, wc = (wv & 1) * 64;

    f32x4 acc[4][4];
    #pragma unroll
    for (int i = 0; i < 4; i++)
        #pragma unroll
        for (int j = 0; j < 4; j++) acc[i][j] = (f32x4){0.f, 0.f, 0.f, 0.f};

    for (int k0 = 0; k0 < K; k0 += 32) {
        #pragma unroll
        for (int j = 0; j < 2; j++) {
            int slot = wv * 128 + j * 64 + lane;     // 0..511
            int row  = slot >> 2;
            int ch   = slot & 3;
            const ushort* ga = A + (size_t)(m0 + row) * K + k0 + ch * 8;
            __builtin_amdgcn_global_load_lds((gas_t)ga, (las_t)(As + slot * 8), 16, 0, 0);
            int brow = n0 + row; if (brow >= N) brow = N - 1;   // clamp (edge tiles)
            const ushort* gb = Bt + (size_t)brow * K + k0 + ch * 8;
            __builtin_amdgcn_global_load_lds((gas_t)gb, (las_t)(Bs + slot * 8), 16, 0, 0);
        }
        __syncthreads();
        bf16x8 af[4], bfr[4];
        #pragma unroll
        for (int i = 0; i < 4; i++)
            af[i] = *(const bf16x8*)(As + (wr + i * 16 + col) * 32 + quad * 8);
        #pragma unroll
        for (int j = 0; j < 4; j++)
            bfr[j] = *(const bf16x8*)(Bs + (wc + j * 16 + col) * 32 + quad * 8);
        #pragma unroll
        for (int i = 0; i < 4; i++)
            #pragma unroll
            for (int j = 0; j < 4; j++)
                acc[i][j] = __builtin_amdgcn_mfma_f32_16x16x32_bf16(af[i], bfr[j], acc[i][j], 0, 0, 0);
        __syncthreads();
    }
    #pragma unroll
    for (int i = 0; i < 4; i++) {
        int gr = m0 + wr + i * 16 + quad * 4;
        #pragma unroll
        for (int j = 0; j < 4; j++) {
            int gc = n0 + wc + j * 16 + col;
            if (gc < N) {
                #pragma unroll
                for (int r = 0; r < 4; r++)
                    C[(size_t)(gr + r) * N + gc] = acc[i][j][r];
            }
        }
    }
}

// ------- fused narrow-N GEMM: hs_bf @ [w_qa_t | w_kva_t]^T -> qa (cols<768) / kin (cols>=768) -------
__global__ __launch_bounds__(256, 4) void gemm_qkva(const ushort* __restrict__ A,
                                                    const ushort* __restrict__ Bt,
                                                    float* __restrict__ qa,
                                                    float* __restrict__ kin,
                                                    int K) {
    __shared__ ushort As[128 * 32];
    __shared__ ushort Bs[64 * 32];
    const int tid  = threadIdx.x;
    const int lane = tid & 63;
    const int wv   = tid >> 6;
    const int col  = lane & 15;
    const int quad = lane >> 4;
    const int m0 = blockIdx.y * 128, n0 = blockIdx.x * 64;
    const int wr = wv * 32;

    f32x4 acc[2][4];
    #pragma unroll
    for (int i = 0; i < 2; i++)
        #pragma unroll
        for (int j = 0; j < 4; j++) acc[i][j] = (f32x4){0.f, 0.f, 0.f, 0.f};

    for (int k0 = 0; k0 < K; k0 += 32) {
        #pragma unroll
        for (int j = 0; j < 2; j++) {                // A: 512 slots, 2/thread
            int slot = j * 256 + tid;
            int row  = slot >> 2;
            int ch   = slot & 3;
            const ushort* ga = A + (size_t)(m0 + row) * K + k0 + ch * 8;
            __builtin_amdgcn_global_load_lds((gas_t)ga, (las_t)(As + slot * 8), 16, 0, 0);
        }
        {                                            // B: 256 slots, 1/thread
            int row = tid >> 2;
            int ch  = tid & 3;
            int brow = n0 + row; if (brow >= NQK) brow = NQK - 1;
            const ushort* gb = Bt + (size_t)brow * K + k0 + ch * 8;
            __builtin_amdgcn_global_load_lds((gas_t)gb, (las_t)(Bs + tid * 8), 16, 0, 0);
        }
        __syncthreads();
        bf16x8 af[2], bfr[4];
        #pragma unroll
        for (int i = 0; i < 2; i++)
            af[i] = *(const bf16x8*)(As + (wr + i * 16 + col) * 32 + quad * 8);
        #pragma unroll
        for (int j = 0; j < 4; j++)
            bfr[j] = *(const bf16x8*)(Bs + (j * 16 + col) * 32 + quad * 8);
        #pragma unroll
        for (int i = 0; i < 2; i++)
            #pragma unroll
            for (int j = 0; j < 4; j++)
                acc[i][j] = __builtin_amdgcn_mfma_f32_16x16x32_bf16(af[i], bfr[j], acc[i][j], 0, 0, 0);
        __syncthreads();
    }
    #pragma unroll
    for (int i = 0; i < 2; i++) {
        int gr = m0 + wr + i * 16 + quad * 4;
        #pragma unroll
        for (int j = 0; j < 4; j++) {
            int gc = n0 + j * 16 + col;
            if (gc < QLORA) {
                #pragma unroll
                for (int r = 0; r < 4; r++)
                    qa[(size_t)(gr + r) * QLORA + gc] = acc[i][j][r];
            } else if (gc < NQK) {
                int kc = gc - QLORA;
                #pragma unroll
                for (int r = 0; r < 4; r++)
                    kin[(size_t)(gr + r) * DQK + kc] = acc[i][j][r];
            }
        }
    }
}

// ---- fused post-GEMM norms: rms(qa)->qa_bf AND rms+rope(kin)->kin_bf, one block per t ----
__global__ __launch_bounds__(256) void post_norms(const float* __restrict__ qa,
                                                  const float* __restrict__ g_qa,
                                                  ushort* __restrict__ qa_bf,
                                                  const float* __restrict__ kin,
                                                  const float* __restrict__ g_kva,
                                                  const int* __restrict__ positions,
                                                  ushort* __restrict__ kin_bf) {
    int t = blockIdx.x, tid = threadIdx.x;
    __shared__ float red[256];
    __shared__ float s_inv;
    // ---- part A: qa RMS (768 cols) ----
    {
        const float* row = qa + (size_t)t * QLORA;
        float ss = 0.f;
        for (int i = tid; i < QLORA; i += 256) { float v = row[i]; ss += v * v; }
        red[tid] = ss; __syncthreads();
        for (int s = 128; s > 0; s >>= 1) { if (tid < s) red[tid] += red[tid + s]; __syncthreads(); }
        if (tid == 0) s_inv = rsqrtf(red[0] / (float)QLORA + EPS);
        __syncthreads();
        float si = s_inv;
        ushort* orow = qa_bf + (size_t)t * QLORA;
        for (int i = tid; i < QLORA; i += 256) orow[i] = f2bf(row[i] * si * g_qa[i]);
    }
    __syncthreads();
    // ---- part B: kin RMS (256) + rope (32) ----
    {
        const float* row = kin + (size_t)t * DQK;
        float v = row[tid];
        red[tid] = v * v; __syncthreads();
        for (int s = 128; s > 0; s >>= 1) { if (tid < s) red[tid] += red[tid + s]; __syncthreads(); }
        if (tid == 0) s_inv = rsqrtf(red[0] / (float)KVLORA + EPS);
        __syncthreads();
        ushort* orow = kin_bf + (size_t)t * DQK;
        orow[tid] = f2bf(v * s_inv * g_kva[tid]);
        if (tid < 16) {
            float pos = (float)positions[t];
            float freq = powf(THETA, -(float)tid / 16.0f);
            float f = pos * freq;
            float c = cosf(f), s = sinf(f);
            float x1 = row[KVLORA + tid], x2 = row[KVLORA + 16 + tid];
            orow[KVLORA + tid]      = f2bf(x1 * c - x2 * s);
            orow[KVLORA + 16 + tid] = f2bf(x2 * c + x1 * s);
        }
    }
}

// --- q_in build (tiled: 16 t-rows per block, w_kc[h] read once per block) ---
#define QTB 16
__global__ __launch_bounds__(256) void build_qin(const float* __restrict__ q,
                                                 const float* __restrict__ w_kc,
                                                 const int* __restrict__ positions,
                                                 ushort* __restrict__ qin) {
    int tb = blockIdx.x * QTB, h = blockIdx.y, tid = threadIdx.x;
    const float scale = 0.10206207261596577f;   // 1/sqrt(96), folded into Q
    __shared__ float qn[QTB][NOPE];
    __shared__ float qp[QTB][ROPE];
    // load 16 q rows (96 floats each)
    for (int i = tid; i < QTB * QHD; i += 256) {
        int r = i / QHD, cidx = i % QHD;
        float v = q[(size_t)(tb + r) * (NH * QHD) + h * QHD + cidx];
        if (cidx < NOPE) qn[r][cidx] = v;
        else             qp[r][cidx - NOPE] = v;
    }
    __syncthreads();
    // each thread owns one latent dim k for all 16 rows
    int k = tid;
    float acc[QTB];
    #pragma unroll
    for (int r = 0; r < QTB; r++) acc[r] = 0.f;
    const float* w = w_kc + (size_t)h * NOPE * KVLORA + k;
    for (int n = 0; n < NOPE; n++) {
        float wval = w[(size_t)n * KVLORA];
        #pragma unroll
        for (int r = 0; r < QTB; r++) acc[r] += qn[r][n] * wval;
    }
    #pragma unroll
    for (int r = 0; r < QTB; r++)
        qin[((size_t)(tb + r) * NH + h) * DQK + k] = f2bf(acc[r] * scale);
    // rope: 16 rows x 16 freqs = 256 threads
    int r = tid >> 4, fi = tid & 15;
    float pos = (float)positions[tb + r];
    float freq = powf(THETA, -(float)fi / 16.0f);
    float f = pos * freq;
    float c = cosf(f), s = sinf(f);
    float x1 = qp[r][fi], x2 = qp[r][16 + fi];
    ushort* orow = qin + ((size_t)(tb + r) * NH + h) * DQK;
    orow[KVLORA + fi]      = f2bf((x1 * c - x2 * s) * scale);
    orow[KVLORA + 16 + fi] = f2bf((x2 * c + x1 * s) * scale);
}

// ---------------- flash MFMA attention (r13-verified, 3 barriers/iter) + fused w_vc ----------------
#define KSTR 296
#define VSTR 72
#define PSTR 72
#define OSTR 264

__global__ __launch_bounds__(256, 2) void flash_attn(const ushort* __restrict__ qin,
                                                     const ushort* __restrict__ kin,
                                                     const ushort* __restrict__ w_vct,
                                                     ushort* __restrict__ o_bf) {
    __shared__ __align__(16) ushort lds[64 * KSTR + 256 * VSTR];
    ushort* krow = lds;
    ushort* vt   = lds + 64 * KSTR;
    ushort* pbuf = lds;                 // alias of krow region (per-wave-private rows)

    const int tid  = threadIdx.x;
    const int lane = tid & 63;
    const int wv   = tid >> 6;
    const int col  = lane & 15;
    const int quad = lane >> 4;
    const int h    = blockIdx.y;
    const int qb   = ((int)gridDim.x - 1 - (int)blockIdx.x) * 64;

    bf16x8 qf[9];
    {
        const ushort* base = qin + ((size_t)(qb + wv * 16 + col) * NH + h) * DQK + quad * 8;
        #pragma unroll
        for (int k = 0; k < 9; k++) qf[k] = *(const bf16x8*)(base + k * 32);
    }

    f32x4 of[16];
    #pragma unroll
    for (int i = 0; i < 16; i++) of[i] = (f32x4){0.f, 0.f, 0.f, 0.f};
    float m_i[4] = {-1e30f, -1e30f, -1e30f, -1e30f};
    float l_i[4] = {0.f, 0.f, 0.f, 0.f};

    for (int s0 = 0; s0 <= qb; s0 += 64) {
        __syncthreads();
        {
            const ushort* src = kin + (size_t)(s0 + lane) * DQK;
            #pragma unroll
            for (int ci = 0; ci < 9; ci++) {
                int c = ci * 4 + wv;
                uint4 u = *(const uint4*)(src + c * 8);
                *(uint4*)(krow + lane * KSTR + c * 8) = u;
                if (c < 32) {
                    const ushort* up = (const ushort*)&u;
                    #pragma unroll
                    for (int j = 0; j < 8; j++)
                        vt[(c * 8 + j) * VSTR + lane] = up[j];
                }
            }
        }
        __syncthreads();
        f32x4 sf[4];
        #pragma unroll
        for (int tc = 0; tc < 4; tc++) sf[tc] = (f32x4){0.f, 0.f, 0.f, 0.f};
        #pragma unroll
        for (int k = 0; k < 9; k++) {
            #pragma unroll
            for (int tc = 0; tc < 4; tc++) {
                bf16x8 bf = *(const bf16x8*)(krow + (tc * 16 + col) * KSTR + k * 32 + quad * 8);
                sf[tc] = __builtin_amdgcn_mfma_f32_16x16x32_bf16(qf[k], bf, sf[tc], 0, 0, 0);
            }
        }
        if (s0 == qb) {
            #pragma unroll
            for (int tc = 0; tc < 4; tc++)
                #pragma unroll
                for (int r = 0; r < 4; r++)
                    if (tc * 16 + col > wv * 16 + quad * 4 + r) sf[tc][r] = -1e30f;
        }
        float mnew[4], alpha[4];
        #pragma unroll
        for (int r = 0; r < 4; r++) {
            float mx = fmaxf(fmaxf(sf[0][r], sf[1][r]), fmaxf(sf[2][r], sf[3][r]));
            mx = fmaxf(mx, __shfl_xor(mx, 1));
            mx = fmaxf(mx, __shfl_xor(mx, 2));
            mx = fmaxf(mx, __shfl_xor(mx, 4));
            mx = fmaxf(mx, __shfl_xor(mx, 8));
            mnew[r] = fmaxf(m_i[r], mx);
            alpha[r] = __expf(m_i[r] - mnew[r]);
            m_i[r] = mnew[r];
        }
        float rsum[4];
        #pragma unroll
        for (int r = 0; r < 4; r++) {
            float s = 0.f;
            #pragma unroll
            for (int tc = 0; tc < 4; tc++) {
                float p = __expf(sf[tc][r] - mnew[r]);
                sf[tc][r] = p;
                s += p;
            }
            s += __shfl_xor(s, 1);
            s += __shfl_xor(s, 2);
            s += __shfl_xor(s, 4);
            s += __shfl_xor(s, 8);
            rsum[r] = s;
        }
        #pragma unroll
        for (int r = 0; r < 4; r++) l_i[r] = l_i[r] * alpha[r] + rsum[r];
        #pragma unroll
        for (int i = 0; i < 16; i++)
            #pragma unroll
            for (int r = 0; r < 4; r++) of[i][r] *= alpha[r];
        __syncthreads();                     // all waves done reading krow (QK^T) before P clobbers it
        #pragma unroll
        for (int tc = 0; tc < 4; tc++)
            #pragma unroll
            for (int r = 0; r < 4; r++)
                pbuf[(wv * 16 + quad * 4 + r) * PSTR + tc * 16 + col] = f2bf(sf[tc][r]);
        // no barrier: pa reads only this wave's own P rows (lgkmcnt orders write->read)
        bf16x8 pa[2];
        #pragma unroll
        for (int ks = 0; ks < 2; ks++)
            pa[ks] = *(const bf16x8*)(pbuf + (wv * 16 + col) * PSTR + ks * 32 + quad * 8);
        #pragma unroll
        for (int nt = 0; nt < 16; nt++) {
            #pragma unroll
            for (int ks = 0; ks < 2; ks++) {
                bf16x8 vb = *(const bf16x8*)(vt + (nt * 16 + col) * VSTR + ks * 32 + quad * 8);
                of[nt] = __builtin_amdgcn_mfma_f32_16x16x32_bf16(pa[ks], vb, of[nt], 0, 0, 0);
            }
        }
    }

    // ---------------- fused epilogue: o_bf[rows, h*64..] = (O/l) @ w_vc[h] ----------------
    __syncthreads();                       // all waves done with krow/vt
    ushort* obuf = lds;                    // 64 x OSTR (fits in krow region: 264 <= 296)
    ushort* wbuf = lds + 64 * KSTR;        // 64 x OSTR (fits in vt region)
    {
        float inv_l[4];
        #pragma unroll
        for (int r = 0; r < 4; r++) inv_l[r] = 1.0f / l_i[r];
        #pragma unroll
        for (int nt = 0; nt < 16; nt++)
            #pragma unroll
            for (int r = 0; r < 4; r++)
                obuf[(wv * 16 + quad * 4 + r) * OSTR + nt * 16 + col] = f2bf(of[nt][r] * inv_l[r]);
        // stage w_vct[h]: 64 rows x 256 k (32 KB), 8 x uint4 per thread, coalesced
        const ushort* wsrc = w_vct + (size_t)h * VDIM * KVLORA;
        #pragma unroll
        for (int i = 0; i < 8; i++) {
            int s = i * 256 + tid;
            int row = s >> 5, ch = s & 31;
            *(uint4*)(wbuf + row * OSTR + ch * 8) = *(const uint4*)(wsrc + (size_t)row * KVLORA + ch * 8);
        }
    }
    __syncthreads();
    f32x4 acc[4];
    #pragma unroll
    for (int j = 0; j < 4; j++) acc[j] = (f32x4){0.f, 0.f, 0.f, 0.f};
    #pragma unroll
    for (int ks = 0; ks < 8; ks++) {
        bf16x8 af = *(const bf16x8*)(obuf + (wv * 16 + col) * OSTR + ks * 32 + quad * 8);
        #pragma unroll
        for (int j = 0; j < 4; j++) {
            bf16x8 bw = *(const bf16x8*)(wbuf + (j * 16 + col) * OSTR + ks * 32 + quad * 8);
            acc[j] = __builtin_amdgcn_mfma_f32_16x16x32_bf16(af, bw, acc[j], 0, 0, 0);
        }
    }
    #pragma unroll
    for (int j = 0; j < 4; j++) {
        int gc = h * VDIM + j * 16 + col;
        #pragma unroll
        for (int r = 0; r < 4; r++)
            o_bf[(size_t)(qb + wv * 16 + quad * 4 + r) * HID + gc] = f2bf(acc[j][r]);
    }
}

extern "C" void kernel_launch(void* const* d_in, const int* in_sizes, int n_in,
                              void* d_out, int out_size, void* d_ws, size_t ws_size,
                              hipStream_t stream) {
    const int*   positions = (const int*)d_in[0];
    const float* hs    = (const float*)d_in[1];
    const float* w_qa  = (const float*)d_in[2];
    const float* g_qa  = (const float*)d_in[3];
    const float* w_qb  = (const float*)d_in[4];
    const float* w_kva = (const float*)d_in[5];
    const float* g_kva = (const float*)d_in[6];
    const float* w_kc  = (const float*)d_in[7];
    const float* w_vc  = (const float*)d_in[8];
    const float* w_o   = (const float*)d_in[9];
    float* out = (float*)d_out;

    float* ws    = (float*)d_ws;
    float* qa    = ws;                               // T*768
    float* q     = qa    + (size_t)TT * QLORA;       // T*3840
    float* kin   = q     + (size_t)TT * NH * QHD;    // T*288
    ushort* ub     = (ushort*)(kin + (size_t)TT * DQK);
    ushort* hs_bf  = ub;                             // T*2560
    ushort* qa_bf  = hs_bf  + (size_t)TT * HID;      // T*768
    ushort* o_bf   = qa_bf  + (size_t)TT * QLORA;    // T*2560
    ushort* kin_bf = o_bf   + (size_t)TT * HID;      // T*288
    ushort* qin_bf = kin_bf + (size_t)TT * DQK;      // T*40*288
    ushort* w_qk_t  = qin_bf + (size_t)TT * NH * DQK;       // 1056*2560 (w_qa_t | w_kva_t)
    ushort* w_qb_t  = w_qk_t + (size_t)NQK * HID;           // 3840*768
    ushort* w_o_t   = w_qb_t + (size_t)(NH * QHD) * QLORA;  // 2560*2560
    ushort* w_vc_t  = w_o_t + (size_t)HID * HID;            // 40*64*256

    // 0. all preprocessing in ONE launch (hs cast + 5 weight transposes)
    prep_all<<<PREP_BLKS, 256, 0, stream>>>(hs, hs_bf, w_qa, w_kva, w_qb, w_o, w_vc,
                                            w_qk_t, w_qb_t, w_o_t, w_vc_t);
    // 1. [qa | kin] = hs @ [w_qa | w_kva]  (N=1056, 17x16=272 blocks)
    gemm_qkva<<<dim3((NQK + 63) / 64, TT / 128), 256, 0, stream>>>(hs_bf, w_qk_t, qa, kin, HID);
    // 2. fused norms: rms(qa)->qa_bf, rms+rope(kin)->kin_bf
    post_norms<<<TT, 256, 0, stream>>>(qa, g_qa, qa_bf, kin, g_kva, positions, kin_bf);
    // 3. q = qa @ w_qb (MFMA)
    gemm_bf16<<<dim3((NH * QHD) / 128, TT / 128), 256, 0, stream>>>(qa_bf, w_qb_t, q, TT, NH * QHD, QLORA);
    // 4. qin_bf = [q_nope @ w_kc[h] | rope(q_pe)] * scale
    build_qin<<<dim3(TT / QTB, NH), 256, 0, stream>>>(q, w_kc, positions, qin_bf);
    // 5. flash MFMA attention with fused w_vc projection -> o_bf directly
    flash_attn<<<dim3(TT / 64, NH), 256, 0, stream>>>(qin_bf, kin_bf, w_vc_t, o_bf);
    // 6. out = o_bf @ w_o (MFMA)
    gemm_bf16<<<dim3(HID / 128, TT / 128), 256, 0, stream>>>(o_bf, w_o_t, out, TT, HID, HID);
}